// Round 7
// baseline (80.632 us; speedup 1.0000x reference)
//
#include <hip/hip_runtime.h>
#include <hip/hip_bf16.h>

typedef unsigned int uint32;
typedef unsigned short u16;

#define NPT 128        // grid nodes per dim
#define RNK 16         // TT rank
#define MIDROW 264     // bf16 elems per LDS row for mid cores (256 + 8 pad) = 528 B
#define MIDROW_U32 132
// LDS: just the two mid cores (edges are read straight from L1-resident global)
#define SMEM_BYTES (2*NPT*MIDROW*2)   // 135168 B -> 1 block/CU

#if defined(__has_builtin)
#if __has_builtin(__builtin_amdgcn_fdot2_f32_bf16)
#define HAVE_BFDOT2 1
#endif
#endif

__device__ __forceinline__ float bl(uint32 u){ return __uint_as_float(u << 16); }
__device__ __forceinline__ float bh(uint32 u){ return __uint_as_float(u & 0xffff0000u); }

__device__ __forceinline__ uint32 pk2(float a, float b){
  __hip_bfloat16 l = __float2bfloat16(a);
  __hip_bfloat16 h = __float2bfloat16(b);
  return (uint32)(*(u16*)&l) | ((uint32)(*(u16*)&h) << 16);
}

#ifdef HAVE_BFDOT2
typedef __bf16 v2bf __attribute__((ext_vector_type(2)));
__device__ __forceinline__ v2bf bc(uint32 u){ return __builtin_bit_cast(v2bf, u); }

// dot of packed-bf16 v (8 u32) with 16 bf16 core elems in two uint4
__device__ __forceinline__ float dot16b(const uint32* vp, uint4 U0, uint4 U1) {
  float s0 = 0.f, s1 = 0.f;
  s0 = __builtin_amdgcn_fdot2_f32_bf16(bc(vp[0]), bc(U0.x), s0, false);
  s0 = __builtin_amdgcn_fdot2_f32_bf16(bc(vp[1]), bc(U0.y), s0, false);
  s0 = __builtin_amdgcn_fdot2_f32_bf16(bc(vp[2]), bc(U0.z), s0, false);
  s0 = __builtin_amdgcn_fdot2_f32_bf16(bc(vp[3]), bc(U0.w), s0, false);
  s1 = __builtin_amdgcn_fdot2_f32_bf16(bc(vp[4]), bc(U1.x), s1, false);
  s1 = __builtin_amdgcn_fdot2_f32_bf16(bc(vp[5]), bc(U1.y), s1, false);
  s1 = __builtin_amdgcn_fdot2_f32_bf16(bc(vp[6]), bc(U1.z), s1, false);
  s1 = __builtin_amdgcn_fdot2_f32_bf16(bc(vp[7]), bc(U1.w), s1, false);
  return s0 + s1;
}
#else
// fallback: unpack + fmaf
__device__ __forceinline__ float dot16(const float* v, uint4 U0, uint4 U1) {
  float s0 = fmaf(v[1],  bh(U0.x), v[0]*bl(U0.x));
  s0 = fmaf(v[2],  bl(U0.y), s0); s0 = fmaf(v[3],  bh(U0.y), s0);
  float s1 = fmaf(v[5],  bh(U0.z), v[4]*bl(U0.z));
  s1 = fmaf(v[6],  bl(U0.w), s1); s1 = fmaf(v[7],  bh(U0.w), s1);
  float s2 = fmaf(v[9],  bh(U1.x), v[8]*bl(U1.x));
  s2 = fmaf(v[10], bl(U1.y), s2); s2 = fmaf(v[11], bh(U1.y), s2);
  float s3 = fmaf(v[13], bh(U1.z), v[12]*bl(U1.z));
  s3 = fmaf(v[14], bl(U1.w), s3); s3 = fmaf(v[15], bh(U1.w), s3);
  return (s0 + s1) + (s2 + s3);
}
#endif

// clamped remap: returns xc in [0, 127]
__device__ __forceinline__ float remap_clamp(float x) {
  float xr = (x + 1.0f) * 0.5f * (float)(NPT - 1);
  return fminf(fmaxf(xr, 0.0f), (float)(NPT - 1));
}

// one middle-dim contraction: v <- v @ ((1-w)*Lo + w*Hi), rows in LDS as [n][j*16+i] bf16.
// n0 = min(floor(xc), 126), w = xc-n0 in [0,1]: rows are always adjacent (lerp(c126,c127,1)
// == c127, identical to floor/ceil form). b128 gather conflicts (~4M cyc) are structural:
// 16B-aligned starts -> 8 four-bank classes; swizzles measured no-op (round 4).
__device__ __forceinline__ void tt_mid(const uint32* __restrict__ base, float xc, float v[16]) {
  int n0 = min((int)xc, NPT - 2);
  float w = xc - (float)n0;
  const uint32* r0 = base + n0 * MIDROW_U32;
  const uint32* r1 = r0 + MIDROW_U32;

#ifdef HAVE_BFDOT2
  // pack v into bf16 pairs once per dim (amortized over 16 j)
  uint32 vp[8];
#pragma unroll
  for (int k = 0; k < 8; ++k) vp[k] = pk2(v[2*k], v[2*k+1]);
#endif

  float nv[16];
#pragma unroll
  for (int j = 0; j < 16; ++j) {
    const uint4* p0 = (const uint4*)(r0 + j * 8);
    const uint4* p1 = (const uint4*)(r1 + j * 8);
    uint4 A0 = p0[0], A1 = p0[1];
    uint4 B0 = p1[0], B1 = p1[1];
#ifdef HAVE_BFDOT2
    float a = dot16b(vp, A0, A1);
    float b = dot16b(vp, B0, B1);
#else
    float a = dot16(v, A0, A1);
    float b = dot16(v, B0, B1);
#endif
    nv[j] = fmaf(w, b - a, a);
  }
#pragma unroll
  for (int j = 0; j < 16; ++j) v[j] = nv[j];
}

// Stage one mid-core chunk t in [0,2048): n=t>>4, q=(t>>1)&7 (j-pair), h=t&1 (i-octet).
// 8x float2 loads [i=8h+k][n][j=2q,2q+1] (stride 2048 fl), pack, 2x ds_write_b128
// (start banks spread over 8 classes -> ~BW-bound, no 16-way b16 write conflicts).
// Written immediately: live state ~16 regs, nothing held across barriers (no spill).
__device__ __forceinline__ void stage_chunk(const float* __restrict__ g,
                                            u16* __restrict__ dst, int t) {
  int n = t >> 4, q = (t >> 1) & 7, h = t & 1;
  const float* s = g + (h * 8) * 2048 + n * 16 + q * 2;
  float2 f[8];
#pragma unroll
  for (int k = 0; k < 8; ++k) f[k] = *(const float2*)(s + k * 2048);
  uint4 w0, w1;
  w0.x = pk2(f[0].x, f[1].x); w0.y = pk2(f[2].x, f[3].x);
  w0.z = pk2(f[4].x, f[5].x); w0.w = pk2(f[6].x, f[7].x);
  w1.x = pk2(f[0].y, f[1].y); w1.y = pk2(f[2].y, f[3].y);
  w1.z = pk2(f[4].y, f[5].y); w1.w = pk2(f[6].y, f[7].y);
  *(uint4*)(dst + n * MIDROW + (2 * q) * 16 + h * 8)     = w0;
  *(uint4*)(dst + n * MIDROW + (2 * q + 1) * 16 + h * 8) = w1;
}

// Round-6 structure + DS-pipe offload: edges (g0, g3: 8 KB each, L1-resident) are read
// straight from global -- dim 0 pre-barrier, dim 3 at the tail -- removing 16 b128 LDS
// reads + all edge staging per thread. Mid staging writes b128 instead of 64x b16.
// LDS (132 KB) caps occupancy at 1 block/CU = 4 waves/SIMD; (1024,1) leaves the
// allocator free up to the 128-reg co-residency bound (round-6 verified no regression).
__global__ __launch_bounds__(1024, 1) void tt_kernel(
    const float* __restrict__ x,  const float* __restrict__ g0,
    const float* __restrict__ g1, const float* __restrict__ g2,
    const float* __restrict__ g3, float* __restrict__ out, int npts)
{
  extern __shared__ char smem[];
  u16* c1 = (u16*)smem;                          // [128][264] bf16
  u16* c2 = c1 + NPT * MIDROW;                   // [128][264] bf16

  const int tid = (int)threadIdx.x;
  const int p0i = (int)blockIdx.x * 1024 + tid;
  const int pc  = min(p0i, npts - 1);

  // hoisted: x load retires under the staging stream
  float4 xv = reinterpret_cast<const float4*>(x)[pc];

  // ---- stage both mid cores: conflict-free chunked b128 path ----
  stage_chunk(g1, c1, tid);
  stage_chunk(g1, c1, tid + 1024);
  stage_chunk(g2, c2, tid);
  stage_chunk(g2, c2, tid + 1024);

  // ---- dim 0 pre-barrier: lerp core0 row-pair straight from global (L1-hot 8 KB) ----
  float v[16];
  {
    float xc = remap_clamp(xv.x);
    int n0 = min((int)xc, NPT - 2);
    float w = xc - (float)n0;
    const float4* L = (const float4*)(g0 + n0 * 16);   // L[0..3]=row n0, L[4..7]=row n0+1
#pragma unroll
    for (int k = 0; k < 4; ++k) {
      float4 l = L[k], h = L[k + 4];
      v[4*k+0] = fmaf(w, h.x - l.x, l.x);
      v[4*k+1] = fmaf(w, h.y - l.y, l.y);
      v[4*k+2] = fmaf(w, h.z - l.z, l.z);
      v[4*k+3] = fmaf(w, h.w - l.w, l.w);
    }
  }

  __syncthreads();                 // c1 + c2 visible

  // ---- dims 1, 2 (the DS-pipe-bound heart) ----
  tt_mid((const uint32*)c1, remap_clamp(xv.y), v);
  tt_mid((const uint32*)c2, remap_clamp(xv.z), v);

  // ---- dim 3: lerp core3 column straight from global (L1-hot 8 KB) and dot ----
  float acc;
  {
    float xc = remap_clamp(xv.w);
    int n0 = min((int)xc, NPT - 2);
    float w = xc - (float)n0;
    float a0 = 0.f, a1 = 0.f, a2 = 0.f, a3 = 0.f;
#pragma unroll
    for (int i = 0; i < 4; ++i) {
#pragma unroll
      for (int k = 0; k < 4; ++k) {
        const float* col = g3 + (4 * i + k) * NPT + n0;   // scalar loads: 4B-aligned safe
        float lo = col[0], hi = col[1];
        float cv = fmaf(w, hi - lo, lo);
        if (k == 0) a0 = fmaf(v[4*i+0], cv, a0);
        else if (k == 1) a1 = fmaf(v[4*i+1], cv, a1);
        else if (k == 2) a2 = fmaf(v[4*i+2], cv, a2);
        else a3 = fmaf(v[4*i+3], cv, a3);
      }
    }
    acc = (a0 + a1) + (a2 + a3);
  }
  if (p0i < npts) out[p0i] = acc;
}

extern "C" void kernel_launch(void* const* d_in, const int* in_sizes, int n_in,
                              void* d_out, int out_size, void* d_ws, size_t ws_size,
                              hipStream_t stream) {
  const float* x  = (const float*)d_in[0];
  const float* g0 = (const float*)d_in[1];
  const float* g1 = (const float*)d_in[2];
  const float* g2 = (const float*)d_in[3];
  const float* g3 = (const float*)d_in[4];
  float* out = (float*)d_out;

  int B = in_sizes[0] / 4;
  // >64 KB dynamic LDS needs the opt-in attribute (host-side call, capture-safe)
  hipFuncSetAttribute(reinterpret_cast<const void*>(tt_kernel),
                      hipFuncAttributeMaxDynamicSharedMemorySize, SMEM_BYTES);
  int block = 1024;
  int grid = (B + block - 1) / block;   // 256 blocks -> 1 per CU
  tt_kernel<<<grid, block, SMEM_BYTES, stream>>>(x, g0, g1, g2, g3, out, B);
}